// Round 6
// baseline (159.233 us; speedup 1.0000x reference)
//
#include <hip/hip_runtime.h>

// Problem constants
#define B_SZ   8
#define T_SEQ  2048
#define C_DIM  1024
#define H_DIM  128

typedef _Float16 half8   __attribute__((ext_vector_type(8)));
typedef _Float16 half4_t __attribute__((ext_vector_type(4)));
typedef float    f32x4   __attribute__((ext_vector_type(4)));

#define MFMA(a, b, c) __builtin_amdgcn_mfma_f32_16x16x32_f16(a, b, c, 0, 0, 0)

// Swizzled physical offset (in halfs) of logical (n, k) within one K-chunk
// of the blocked weight layout WTb[kb][...], kb = k/32.  Rows pack 2 n's
// (128 B = all 32 banks); 16B slots XOR'd by row -> all MFMA fragment
// reads and the linear global_load_lds staging are 2-way (free) on banks.
__device__ __forceinline__ int wphys(int n, int k) {
    int r = n >> 1;                          // packed row, 64 halfs each
    int slot = ((n & 1) << 2) | (k >> 3);    // 16B slot 0..7
    return r * 64 + ((slot ^ (r & 7)) << 3) + (k & 7);
}

// async global->LDS, 16B per lane (Common-mistake #1: compiler never emits
// this automatically).  Fallback keeps compilation safe.
__device__ __forceinline__ void gld16(const _Float16* g, _Float16* l) {
#if __has_builtin(__builtin_amdgcn_global_load_lds)
    __builtin_amdgcn_global_load_lds(
        (const __attribute__((address_space(1))) void*)g,
        (__attribute__((address_space(3))) void*)l, 16, 0, 0);
#else
    *(half8*)l = *(const half8*)g;
#endif
}

// ---------------------------------------------------------------------------
// prep: W [C][H] fp32 -> WTb: K-blocked, bank-swizzled fp16 layout.
// WTb[kb][wphys(n, k&31)], kb = k>>5, n = w*128 + h  (384 n total).
// Each 24 KiB K-chunk is contiguous -> proj stages it with linear
// global_load_lds while reads stay conflict-free (rule #21: linear dest +
// pre-swizzled source + swizzle on read).  grid (32,3) x 256.
// ---------------------------------------------------------------------------
__global__ __launch_bounds__(256) void prep_kernel(
    const float* __restrict__ Wk, const float* __restrict__ Wq,
    const float* __restrict__ Wv, _Float16* __restrict__ WTb)
{
    __shared__ _Float16 tile[64][72];    // [h][c] 64x64, 16B-aligned rows

    const int w = blockIdx.y;
    const float* W = (w == 0) ? Wk : (w == 1) ? Wq : Wv;

    const int bx = blockIdx.x;           // 0..31
    const int c0 = (bx >> 1) * 64;       // 16 c-tiles (c = k)
    const int h0 = (bx & 1) * 64;        // 2 h-tiles
    const int t  = threadIdx.x;

    // read: coalesced along h (float4), scatter-transpose into LDS
    {
        const int hl = (t & 15) * 4;
        const int cl = t >> 4;
        #pragma unroll
        for (int p = 0; p < 4; ++p) {
            int c = cl + p * 16;
            float4 f = *(const float4*)(W + (size_t)(c0 + c) * H_DIM + h0 + hl);
            tile[hl + 0][c] = (_Float16)f.x;
            tile[hl + 1][c] = (_Float16)f.y;
            tile[hl + 2][c] = (_Float16)f.z;
            tile[hl + 3][c] = (_Float16)f.w;
        }
    }
    __syncthreads();
    // write: half8 per (h, k8) into the blocked-swizzled layout
    #pragma unroll
    for (int it = 0; it < 2; ++it) {
        int id = it * 256 + t;           // 0..511
        int hh = id >> 3, cs = id & 7;
        int n  = w * 128 + h0 + hh;
        int k8 = c0 + cs * 8;
        int kb = k8 >> 5;
        half8 v = *(const half8*)(&tile[hh][cs * 8]);
        *(half8*)(WTb + (size_t)kb * 12288 + wphys(n, k8 & 31)) = v;
    }
}

// ---------------------------------------------------------------------------
// proj: out[m][n'] = sum_k x[m][k]*W'[k][n'], M=16384, N'=384 (3 fused
// weights), K=1024.  R14 REDESIGN per R5 counters (MfmaUtil 10%, VALUBusy
// 7%, HBM 14%, occupancy 15% -> pure latency/stall bound; staging exposed
// between barriers):
//   * W staged via async global_load_lds width-16 (no VGPR round-trip)
//     from the pre-swizzled WTb -> fragment reads 2-way bank-free.
//   * 2-phase double-buffered K-loop (BK=32), ONE barrier per step, stage
//     issued BEFORE compute so L2/L3 latency hides under MFMA+ds_read.
//   * x read once (3-in-1 kept), reg-staged (fp32->fp16 cvt), 1 float4/
//     thread/step issued first in the step.
//   * 512 thr, 8 waves each owning 64 rows x 48 cols; grid 256 -> one
//     block per CU, 8 waves/CU; LDS 56 KiB.
// ---------------------------------------------------------------------------
__global__ __launch_bounds__(512, 2) void proj_kernel(
    const float* __restrict__ x, const _Float16* __restrict__ WTb,
    _Float16* __restrict__ q, _Float16* __restrict__ k, _Float16* __restrict__ vT)
{
    __shared__ __align__(16) _Float16 wl[2][12288];  // 48 KiB  W double-buffer
    __shared__ __align__(16) _Float16 xs[2][2048];   //  8 KiB  x double-buffer

    const int m0 = blockIdx.x * 64;
    const int t  = threadIdx.x;          // 0..511
    const int wave = t >> 6, lane = t & 63;
    const int quad = lane >> 4, l15 = lane & 15;

    f32x4 acc[4][3] = {};

    // x staging geometry: thread t handles m = t>>3, k-quartet (t&7)*4
    const int xm  = t >> 3;
    const int xkq = (t & 7) * 4;
    const float* xsrc = x + (size_t)(m0 + xm) * C_DIM + xkq;
    const int xds = wphys(xm, xkq) & ~0;             // half4-aligned (8B)

    // fragment offsets (constant across steps; only the buffer flips)
    int aoff[4], boff[3];
    #pragma unroll
    for (int i = 0; i < 4; ++i) aoff[i] = wphys(i * 16 + l15, quad * 8);
    #pragma unroll
    for (int j = 0; j < 3; ++j) boff[j] = wphys(wave * 48 + j * 16 + l15, quad * 8);

    // -- prologue: stage step 0 into buffer 0 --
    {
        float4 f = *(const float4*)(xsrc);
        gld16(WTb + 0 * 4096 + t * 8, &wl[0][0 * 4096 + t * 8]);
        gld16(WTb + 1 * 4096 + t * 8, &wl[0][1 * 4096 + t * 8]);
        gld16(WTb + 2 * 4096 + t * 8, &wl[0][2 * 4096 + t * 8]);
        half4_t hv = { (_Float16)f.x, (_Float16)f.y, (_Float16)f.z, (_Float16)f.w };
        *(half4_t*)(&xs[0][xds]) = hv;
    }
    __syncthreads();

    #define PROJ_COMPUTE(BUF)                                                  \
        {                                                                      \
            half8 af[4], bf[3];                                                \
            _Pragma("unroll")                                                  \
            for (int i = 0; i < 4; ++i)                                        \
                af[i] = *(const half8*)(&xs[BUF][aoff[i]]);                    \
            _Pragma("unroll")                                                  \
            for (int j = 0; j < 3; ++j)                                        \
                bf[j] = *(const half8*)(&wl[BUF][boff[j]]);                    \
            _Pragma("unroll")                                                  \
            for (int i = 0; i < 4; ++i)                                        \
                _Pragma("unroll")                                              \
                for (int j = 0; j < 3; ++j)                                    \
                    acc[i][j] = MFMA(af[i], bf[j], acc[i][j]);                 \
        }

    #define PROJ_STAGE(S, BUF)                                                 \
        {                                                                      \
            float4 f = *(const float4*)(xsrc + (S) * 32);                      \
            const _Float16* wsrc = WTb + (size_t)(S) * 12288 + t * 8;          \
            gld16(wsrc,        &wl[BUF][t * 8]);                               \
            gld16(wsrc + 4096, &wl[BUF][4096 + t * 8]);                        \
            gld16(wsrc + 8192, &wl[BUF][8192 + t * 8]);                        \
            xf_pend = f;                                                       \
        }

    float4 xf_pend;
    #pragma unroll 1
    for (int s = 0; s < 32; s += 2) {
        // phase A: stage s+1 -> buf1, compute buf0 (step s)
        PROJ_STAGE(s + 1, 1);
        PROJ_COMPUTE(0);
        {
            half4_t hv = { (_Float16)xf_pend.x, (_Float16)xf_pend.y,
                           (_Float16)xf_pend.z, (_Float16)xf_pend.w };
            *(half4_t*)(&xs[1][xds]) = hv;
        }
        __syncthreads();
        // phase B: stage s+2 -> buf0 (if any), compute buf1 (step s+1)
        if (s + 2 < 32) {
            PROJ_STAGE(s + 2, 0);
            PROJ_COMPUTE(1);
            half4_t hv = { (_Float16)xf_pend.x, (_Float16)xf_pend.y,
                           (_Float16)xf_pend.z, (_Float16)xf_pend.w };
            *(half4_t*)(&xs[0][xds]) = hv;
        } else {
            PROJ_COMPUTE(1);
        }
        __syncthreads();
    }
    #undef PROJ_COMPUTE
    #undef PROJ_STAGE

    // epilogue: n' < 128 -> k, < 256 -> q, else vT (transposed)
    #pragma unroll
    for (int i = 0; i < 4; ++i) {
        int grow = m0 + i * 16 + quad * 4;
        #pragma unroll
        for (int j = 0; j < 3; ++j) {
            int n = wave * 48 + j * 16 + l15;
            if (n < 256) {
                _Float16* o = (n < 128) ? k : q;
                int col = n & 127;
                #pragma unroll
                for (int r = 0; r < 4; ++r)
                    o[(size_t)(grow + r) * H_DIM + col] = (_Float16)acc[i][j][r];
            } else {
                int h  = n - 256;
                int bb = grow >> 11, tp = grow & (T_SEQ - 1);
                half4_t hv = { (_Float16)acc[i][j][0], (_Float16)acc[i][j][1],
                               (_Float16)acc[i][j][2], (_Float16)acc[i][j][3] };
                *(half4_t*)(vT + ((size_t)bb * H_DIM + h) * T_SEQ + tp) = hv;
            }
        }
    }
}

// ---------------------------------------------------------------------------
// attn: 4 waves/block, qtile 64, kv tile 64, kv-chunk 512.  EXACT R0 version
// (proven ~30 us) — single-variable attribution of the proj change.
// ---------------------------------------------------------------------------
__global__ __launch_bounds__(256, 3) void attn_kernel(
    const _Float16* __restrict__ q, const _Float16* __restrict__ k,
    const _Float16* __restrict__ vT,
    _Float16* __restrict__ pO, float* __restrict__ ml, float* __restrict__ out)
{
    __shared__ _Float16 ks [64][136];    // 17408 B
    __shared__ _Float16 vts[128][72];    // 18432 B
    __shared__ _Float16 ps [4][16][72];  //  9216 B   (total 45056)

    const int n = blockIdx.x;
    const int b = n & 7;
    const int u = n >> 3;                // 0..79, heavy-first

    int qt = 31, c = 0;
    {
        int acc = 0;
        #pragma unroll 1
        while (true) {
            int nch = (qt >> 3) + 1;
            if (u < acc + nch) { c = u - acc; break; }
            acc += nch; --qt;
        }
    }
    const bool partial = (qt >= 8);

    const int kt0 = c * 8;
    const int kt1 = min(qt, c * 8 + 7);

    const int t = threadIdx.x;
    const int wave = t >> 6, lane = t & 63;
    const int quad = lane >> 4, l15 = lane & 15;
    const int qrow0 = qt * 64 + wave * 16;

    const _Float16* qb = q  + (size_t)b * T_SEQ * H_DIM;
    const _Float16* kp = k  + (size_t)b * T_SEQ * H_DIM;
    const _Float16* vp = vT + (size_t)b * H_DIM * T_SEQ;

    half8 aq[4];
    #pragma unroll
    for (int i = 0; i < 4; ++i) {
        half8 v = *(const half8*)(qb + (size_t)(qrow0 + l15) * H_DIM + i * 32 + quad * 8);
        #pragma unroll
        for (int j = 0; j < 8; ++j) v[j] = v[j] * (_Float16)0.088388347648318447f;
        aq[i] = v;
    }

    f32x4 accO[8] = {};
    float lrun[4] = {0.0f, 0.0f, 0.0f, 0.0f};

    const int krow = t >> 4, kseg = t & 15;
    const int vrow = t >> 3, vseg = t & 7;

    for (int kt = kt0; kt <= kt1; ++kt) {
        const int kv0 = kt * 64;
        __syncthreads();
        #pragma unroll
        for (int p = 0; p < 4; ++p) {
            int row = p * 16 + krow;
            *(half8*)(&ks[row][kseg * 8]) =
                *(const half8*)(kp + (size_t)(kv0 + row) * H_DIM + kseg * 8);
        }
        #pragma unroll
        for (int p = 0; p < 4; ++p) {
            int h = p * 32 + vrow;
            *(half8*)(&vts[h][vseg * 8]) =
                *(const half8*)(vp + (size_t)h * T_SEQ + kv0 + vseg * 8);
        }
        __syncthreads();

        f32x4 sacc[4] = {};
        #pragma unroll
        for (int kbi = 0; kbi < 4; ++kbi) {
            #pragma unroll
            for (int nt = 0; nt < 4; ++nt) {
                half8 bf = *(const half8*)(&ks[nt * 16 + l15][kbi * 32 + quad * 8]);
                sacc[nt] = MFMA(aq[kbi], bf, sacc[nt]);
            }
        }

        if (kv0 + 63 > qrow0) {
            #pragma unroll
            for (int nt = 0; nt < 4; ++nt) {
                int key = kv0 + nt * 16 + l15;
                #pragma unroll
                for (int r = 0; r < 4; ++r) {
                    int qr = qrow0 + quad * 4 + r;
                    if (key > qr) sacc[nt][r] = -1.0e30f;
                }
            }
        }

        #pragma unroll
        for (int nt = 0; nt < 4; ++nt)
            #pragma unroll
            for (int r = 0; r < 4; ++r) {
                float p = __expf(sacc[nt][r]);
                lrun[r] += p;
                ps[wave][quad * 4 + r][nt * 16 + l15] = (_Float16)p;
            }

        half8 pf0 = *(const half8*)(&ps[wave][l15][quad * 8]);
        half8 pf1 = *(const half8*)(&ps[wave][l15][32 + quad * 8]);
        #pragma unroll
        for (int nt = 0; nt < 8; ++nt) {
            half8 vf0 = *(const half8*)(&vts[nt * 16 + l15][quad * 8]);
            half8 vf1 = *(const half8*)(&vts[nt * 16 + l15][32 + quad * 8]);
            accO[nt] = MFMA(pf0, vf0, accO[nt]);
            accO[nt] = MFMA(pf1, vf1, accO[nt]);
        }
    }

    #pragma unroll
    for (int r = 0; r < 4; ++r) {
        lrun[r] += __shfl_xor(lrun[r], 1);
        lrun[r] += __shfl_xor(lrun[r], 2);
        lrun[r] += __shfl_xor(lrun[r], 4);
        lrun[r] += __shfl_xor(lrun[r], 8);
    }

    if (partial) {
        const int pid = b * 72 + u;
        const int urow = wave * 16 + quad * 4;
        #pragma unroll
        for (int nt = 0; nt < 8; ++nt)
            #pragma unroll
            for (int r = 0; r < 4; ++r)
                pO[(size_t)pid * 8192 + (urow + r) * 128 + nt * 16 + l15]
                    = (_Float16)accO[nt][r];
        if (l15 == 0) {
            #pragma unroll
            for (int r = 0; r < 4; ++r)
                ml[(size_t)pid * 64 + urow + r] = lrun[r];
        }
    } else {
        float invl[4];
        #pragma unroll
        for (int r = 0; r < 4; ++r) invl[r] = 1.0f / lrun[r];
        #pragma unroll
        for (int nt = 0; nt < 8; ++nt)
            #pragma unroll
            for (int r = 0; r < 4; ++r)
                out[((size_t)b * T_SEQ + qrow0 + quad * 4 + r) * H_DIM + nt * 16 + l15]
                    = accO[nt][r] * invl[r];
    }
}

// ---------------------------------------------------------------------------
// combine: out = (sum_c pO[c]) / (sum_c l[c]); nc = qt/8+1 in 2..4. (unchanged)
// ---------------------------------------------------------------------------
__global__ __launch_bounds__(256) void attn_combine(
    const _Float16* __restrict__ pO, const float* __restrict__ ml,
    float* __restrict__ out)
{
    const int n  = blockIdx.x;
    const int b  = n & 7;
    const int m  = n >> 3;               // 0..95
    const int rg = m & 3;
    const int qt = 8 + (m >> 2);         // 8..31
    const int nc = (qt >> 3) + 1;        // 2..4

    int u0 = 0;
    #pragma unroll 1
    for (int q2 = 31; q2 > qt; --q2) u0 += (q2 >> 3) + 1;
    const size_t pid0 = (size_t)b * 72 + u0;

    const int t   = threadIdx.x;
    const int row = rg * 16 + (t >> 4);
    const int h   = (t & 15) * 8;

    float lsum = 0.0f;
    #pragma unroll 1
    for (int c = 0; c < nc; ++c)
        lsum += ml[(pid0 + c) * 64 + row];

    float acc[8] = {};
    #pragma unroll 1
    for (int c = 0; c < nc; ++c) {
        half8 po = *(const half8*)(pO + (pid0 + c) * 8192 + row * 128 + h);
        #pragma unroll
        for (int j = 0; j < 8; ++j) acc[j] += (float)po[j];
    }

    const float inv = 1.0f / lsum;
    float* op = out + ((size_t)b * T_SEQ + qt * 64 + row) * H_DIM + h;
    f32x4 o0 = { acc[0] * inv, acc[1] * inv, acc[2] * inv, acc[3] * inv };
    f32x4 o1 = { acc[4] * inv, acc[5] * inv, acc[6] * inv, acc[7] * inv };
    *(f32x4*)(op)     = o0;
    *(f32x4*)(op + 4) = o1;
}

// ---------------------------------------------------------------------------
extern "C" void kernel_launch(void* const* d_in, const int* in_sizes, int n_in,
                              void* d_out, int out_size, void* d_ws, size_t ws_size,
                              hipStream_t stream)
{
    const float* x  = (const float*)d_in[0];
    const float* Wk = (const float*)d_in[1];
    const float* Wq = (const float*)d_in[2];
    const float* Wv = (const float*)d_in[3];
    float* out = (float*)d_out;

    _Float16* ws = (_Float16*)d_ws;
    const size_t NQKV = (size_t)B_SZ * T_SEQ * H_DIM;          // 2,097,152
    _Float16* q_ws  = ws;
    _Float16* k_ws  = ws + NQKV;
    _Float16* vT_ws = ws + 2 * NQKV;
    _Float16* wt_ws = ws + 3 * NQKV;                           // 3*C*H halfs (blocked-swizzled)
    _Float16* pO_ws = wt_ws + 3 * (size_t)(C_DIM * H_DIM);     // 576 units * 8192 halfs
    float*    ml_ws = (float*)(pO_ws + (size_t)576 * 8192);    // 576 * 64 floats

    prep_kernel <<<dim3(32, 3), 256, 0, stream>>>(Wk, Wq, Wv, wt_ws);
    proj_kernel <<<256, 512, 0, stream>>>(x, wt_ws, q_ws, k_ws, vT_ws);
    attn_kernel <<<640, 256, 0, stream>>>(q_ws, k_ws, vT_ws, pO_ws, ml_ws, out);
    attn_combine<<<768, 256, 0, stream>>>(pO_ws, ml_ws, out);
}